// Round 4
// baseline (281.730 us; speedup 1.0000x reference)
//
#include <hip/hip_runtime.h>

#define C_DIM  384
#define HEADS  6
#define HD     64
#define FF_DIM 1536
#define LN_EPS 1e-3f
#define TSEQ   2048
#define BATCH  4
#define LOG2E  1.4426950408889634f

typedef __attribute__((ext_vector_type(4))) float          f32x4;
typedef __attribute__((ext_vector_type(4))) float          float4_t;
typedef __attribute__((ext_vector_type(8))) short          bfrag;     // 8 bf16
typedef __attribute__((ext_vector_type(4))) unsigned short ushort4_t;
typedef __attribute__((ext_vector_type(8))) unsigned short ushort8_t;

__device__ inline unsigned short f2bf(float f) {
    unsigned int u = __builtin_bit_cast(unsigned int, f);
    u += 0x7fff + ((u >> 16) & 1);          // RNE
    return (unsigned short)(u >> 16);
}

// ---------------------------------------------------------------------------
// Transpose + convert weight: W[K][N] f32 -> Wt[N][K] bf16. K,N % 32 == 0.
// block (32,8), grid (N/32, K/32).
// ---------------------------------------------------------------------------
__global__ __launch_bounds__(256)
void transpose_w(const float* __restrict__ W, unsigned short* __restrict__ Wt, int K, int N)
{
    __shared__ float tile[32][33];
    const int tx = threadIdx.x, ty = threadIdx.y;
    const int n0 = blockIdx.x * 32, k0 = blockIdx.y * 32;
    #pragma unroll
    for (int i = 0; i < 32; i += 8)
        tile[ty + i][tx] = W[(size_t)(k0 + ty + i) * N + n0 + tx];
    __syncthreads();
    #pragma unroll
    for (int i = 0; i < 32; i += 8)
        Wt[(size_t)(n0 + ty + i) * K + k0 + tx] = f2bf(tile[tx][ty + i]);
}

// ---------------------------------------------------------------------------
// f32 -> bf16 bulk convert, 4 elems/thread.
// ---------------------------------------------------------------------------
__global__ __launch_bounds__(256)
void cvt_f32_bf16_x4(const float* __restrict__ in, unsigned short* __restrict__ out, int n4)
{
    int i = blockIdx.x * 256 + threadIdx.x;
    if (i >= n4) return;
    float4_t v = ((const float4_t*)in)[i];
    ushort4_t o = { f2bf(v.x), f2bf(v.y), f2bf(v.z), f2bf(v.w) };
    ((ushort4_t*)out)[i] = o;
}

// ---------------------------------------------------------------------------
// V transpose: qkv v-columns -> vt[bh][d][t] bf16.
// block (32,8), grid (T/32, HD/32, B*HEADS).
// ---------------------------------------------------------------------------
__global__ __launch_bounds__(256)
void vtrans_kernel(const unsigned short* __restrict__ qkv, unsigned short* __restrict__ vt)
{
    __shared__ unsigned short tile[32][34];
    const int tx = threadIdx.x, ty = threadIdx.y;
    const int bh = blockIdx.z, b = bh / HEADS, h = bh % HEADS;
    const int t0 = blockIdx.x * 32, d0 = blockIdx.y * 32;
    #pragma unroll
    for (int i = 0; i < 32; i += 8)
        tile[ty + i][tx] = qkv[(size_t)(b * TSEQ + t0 + ty + i) * 1152 + 2 * C_DIM + h * HD + d0 + tx];
    __syncthreads();
    #pragma unroll
    for (int i = 0; i < 32; i += 8)
        vt[((size_t)bh * HD + d0 + ty + i) * TSEQ + t0 + tx] = tile[tx][ty + i];
}

// ---------------------------------------------------------------------------
// Direct-from-L2 bf16 MFMA GEMM. C[M,N] = A[M,K] @ Bt[N,K]^T (+bias)(+relu).
// 256 thr = 4 waves along M; wave computes 64 x (16*NFR) via 4 x NFR frags.
// No LDS, no barriers; fragments double-buffered from global (L2-resident).
// ---------------------------------------------------------------------------
template<int NFR, int OBF16, int BIAS, int RELU>
__global__ __launch_bounds__(256)
void gemm_l2(const unsigned short* __restrict__ A, const unsigned short* __restrict__ Bt,
             const float* __restrict__ bias, void* __restrict__ Cv,
             int M, int N, int K)
{
    const int t = threadIdx.x, lane = t & 63, w = t >> 6;
    const int ln16 = lane & 15, hi16 = lane >> 4;
    const int row0 = blockIdx.y * 256 + w * 64;
    const int col0 = blockIdx.x * (16 * NFR);
    const unsigned short* Ab = A  + (size_t)(row0 + ln16) * K + hi16 * 8;
    const unsigned short* Bb = Bt + (size_t)(col0 + ln16) * K + hi16 * 8;
    const int KS = K >> 5;                 // 32-wide k-chunks; KS is even here

    f32x4 acc[4][NFR] = {};
    bfrag a0[4], b0[NFR], a1[4], b1[NFR];

    #pragma unroll
    for (int rf = 0; rf < 4; ++rf) a0[rf] = *(const bfrag*)(Ab + (size_t)rf * 16 * K);
    #pragma unroll
    for (int cf = 0; cf < NFR; ++cf) b0[cf] = *(const bfrag*)(Bb + (size_t)cf * 16 * K);

    for (int ks = 0; ks < KS; ks += 2) {
        {   // prefetch ks+1
            const unsigned short* An = Ab + (ks + 1) * 32;
            const unsigned short* Bn = Bb + (ks + 1) * 32;
            #pragma unroll
            for (int rf = 0; rf < 4; ++rf) a1[rf] = *(const bfrag*)(An + (size_t)rf * 16 * K);
            #pragma unroll
            for (int cf = 0; cf < NFR; ++cf) b1[cf] = *(const bfrag*)(Bn + (size_t)cf * 16 * K);
        }
        #pragma unroll
        for (int rf = 0; rf < 4; ++rf)
            #pragma unroll
            for (int cf = 0; cf < NFR; ++cf)
                acc[rf][cf] = __builtin_amdgcn_mfma_f32_16x16x32_bf16(a0[rf], b0[cf], acc[rf][cf], 0, 0, 0);
        if (ks + 2 < KS) {  // prefetch ks+2
            const unsigned short* An = Ab + (ks + 2) * 32;
            const unsigned short* Bn = Bb + (ks + 2) * 32;
            #pragma unroll
            for (int rf = 0; rf < 4; ++rf) a0[rf] = *(const bfrag*)(An + (size_t)rf * 16 * K);
            #pragma unroll
            for (int cf = 0; cf < NFR; ++cf) b0[cf] = *(const bfrag*)(Bn + (size_t)cf * 16 * K);
        }
        #pragma unroll
        for (int rf = 0; rf < 4; ++rf)
            #pragma unroll
            for (int cf = 0; cf < NFR; ++cf)
                acc[rf][cf] = __builtin_amdgcn_mfma_f32_16x16x32_bf16(a1[rf], b1[cf], acc[rf][cf], 0, 0, 0);
    }

    #pragma unroll
    for (int cf = 0; cf < NFR; ++cf) {
        const int col = col0 + cf * 16 + ln16;
        const float bv = BIAS ? bias[col] : 0.0f;
        #pragma unroll
        for (int rf = 0; rf < 4; ++rf) {
            #pragma unroll
            for (int e = 0; e < 4; ++e) {
                const int row = row0 + rf * 16 + hi16 * 4 + e;
                float v = acc[rf][cf][e] + bv;
                if (RELU) v = fmaxf(v, 0.0f);
                if (OBF16) ((unsigned short*)Cv)[(size_t)row * N + col] = f2bf(v);
                else       ((float*)Cv)[(size_t)row * N + col] = v;
            }
        }
    }
}

// ---------------------------------------------------------------------------
// Wave-independent flash attention. 64-thread blocks (1 wave), 32 Q-rows/wave.
// K/V/Q read directly from L2; no barriers. Deferred l-sum; defer-max (THR=8
// in log2 units). P bounced through a wave-private LDS strip.
// Grid: 1536 blocks; XCD-swizzled so each XCD owns 3 (b,h) pairs.
// ---------------------------------------------------------------------------
__global__ __launch_bounds__(64)
void attn_kernel(const unsigned short* __restrict__ qkv,
                 const unsigned short* __restrict__ vt,
                 unsigned short* __restrict__ att)
{
    __shared__ __align__(16) unsigned short Ps[32][72];
    const int lane = threadIdx.x;
    const int ln16 = lane & 15, hi16 = lane >> 4;
    const int bid = blockIdx.x;            // 0..1535
    const int xcd = bid & 7;
    const int i2  = bid >> 3;              // 0..191
    const int bh  = xcd * 3 + (i2 >> 6);   // 3 bh per XCD -> 1.5 MB KV per L2
    const int qw  = 63 - (i2 & 63);        // descending: heavy waves first
    const int b   = bh / HEADS, h = bh % HEADS;
    const int tok0 = qw * 32;
    const size_t qrow0 = (size_t)b * TSEQ;

    // Q fragments (held in regs for whole kernel)
    bfrag qf[2][2];
    #pragma unroll
    for (int rf = 0; rf < 2; ++rf)
        #pragma unroll
        for (int ks = 0; ks < 2; ++ks)
            qf[rf][ks] = *(const bfrag*)&qkv[(qrow0 + tok0 + rf * 16 + ln16) * 1152 + h * HD + ks * 32 + hi16 * 8];

    f32x4 acc[2][4] = {};
    float mrow[2][4], lrow[2][4];
    #pragma unroll
    for (int rf = 0; rf < 2; ++rf)
        #pragma unroll
        for (int e = 0; e < 4; ++e) { mrow[rf][e] = -1e30f; lrow[rf][e] = 0.0f; }

    const int NT = (qw >> 1) + 1;
    const unsigned short* Kbase = qkv + qrow0 * 1152 + C_DIM + h * HD;
    const unsigned short* Vbase = vt + (size_t)bh * HD * TSEQ;

    bfrag kf[4][2];
    #pragma unroll
    for (int jt = 0; jt < 4; ++jt)
        #pragma unroll
        for (int ks = 0; ks < 2; ++ks)
            kf[jt][ks] = *(const bfrag*)&Kbase[(size_t)(jt * 16 + ln16) * 1152 + ks * 32 + hi16 * 8];

    for (int kt = 0; kt < NT; ++kt) {
        // ---- S = Q K^T ----
        f32x4 sf[2][4] = {};
        #pragma unroll
        for (int jt = 0; jt < 4; ++jt)
            #pragma unroll
            for (int ks = 0; ks < 2; ++ks) {
                sf[0][jt] = __builtin_amdgcn_mfma_f32_16x16x32_bf16(qf[0][ks], kf[jt][ks], sf[0][jt], 0, 0, 0);
                sf[1][jt] = __builtin_amdgcn_mfma_f32_16x16x32_bf16(qf[1][ks], kf[jt][ks], sf[1][jt], 0, 0, 0);
            }

        // ---- V fragments: issue early, consumed after softmax ----
        bfrag vf[4][2];
        #pragma unroll
        for (int dt = 0; dt < 4; ++dt)
            #pragma unroll
            for (int ks = 0; ks < 2; ++ks)
                vf[dt][ks] = *(const bfrag*)&Vbase[(size_t)(dt * 16 + ln16) * TSEQ + kt * 64 + ks * 32 + hi16 * 8];

        // ---- scale (to log2 domain) + causal mask on last tile ----
        const bool last = (kt == NT - 1);
        float p[2][4][4];
        #pragma unroll
        for (int rf = 0; rf < 2; ++rf)
            #pragma unroll
            for (int jt = 0; jt < 4; ++jt)
                #pragma unroll
                for (int e = 0; e < 4; ++e) {
                    float sv = sf[rf][jt][e] * (0.125f * LOG2E);
                    if (last) {
                        const int key = kt * 64 + jt * 16 + ln16;
                        const int row = tok0 + rf * 16 + hi16 * 4 + e;
                        if (key > row) sv = -1e30f;
                    }
                    p[rf][jt][e] = sv;
                }

        // ---- defer-max check (lane-local max only) ----
        float lmax[2][4];
        bool need = false;
        #pragma unroll
        for (int rf = 0; rf < 2; ++rf)
            #pragma unroll
            for (int e = 0; e < 4; ++e) {
                float mx = fmaxf(fmaxf(p[rf][0][e], p[rf][1][e]), fmaxf(p[rf][2][e], p[rf][3][e]));
                lmax[rf][e] = mx;
                need = need || (mx > mrow[rf][e] + 8.0f);
            }
        if (__any(need)) {
            #pragma unroll
            for (int rf = 0; rf < 2; ++rf)
                #pragma unroll
                for (int e = 0; e < 4; ++e) {
                    float rm = lmax[rf][e];
                    rm = fmaxf(rm, __shfl_xor(rm, 1));
                    rm = fmaxf(rm, __shfl_xor(rm, 2));
                    rm = fmaxf(rm, __shfl_xor(rm, 4));
                    rm = fmaxf(rm, __shfl_xor(rm, 8));
                    const float mn = fmaxf(mrow[rf][e], rm);
                    const float corr = exp2f(mrow[rf][e] - mn);
                    mrow[rf][e] = mn;
                    lrow[rf][e] *= corr;
                    #pragma unroll
                    for (int dt = 0; dt < 4; ++dt) acc[rf][dt][e] *= corr;
                }
        }

        // ---- prefetch next K tile under the exp/PV phase ----
        if (kt + 1 < NT) {
            const unsigned short* Kn = Kbase + (size_t)(kt + 1) * 64 * 1152;
            #pragma unroll
            for (int jt = 0; jt < 4; ++jt)
                #pragma unroll
                for (int ks = 0; ks < 2; ++ks)
                    kf[jt][ks] = *(const bfrag*)&Kn[(size_t)(jt * 16 + ln16) * 1152 + ks * 32 + hi16 * 8];
        }

        // ---- exp, per-lane l partial, P -> LDS ----
        #pragma unroll
        for (int rf = 0; rf < 2; ++rf)
            #pragma unroll
            for (int jt = 0; jt < 4; ++jt)
                #pragma unroll
                for (int e = 0; e < 4; ++e) {
                    const float pe = exp2f(p[rf][jt][e] - mrow[rf][e]);
                    lrow[rf][e] += pe;
                    Ps[rf * 16 + hi16 * 4 + e][jt * 16 + ln16] = f2bf(pe);
                }

        // ---- PV ----
        bfrag pf[2][2];
        #pragma unroll
        for (int rf = 0; rf < 2; ++rf)
            #pragma unroll
            for (int ks = 0; ks < 2; ++ks)
                pf[rf][ks] = *(const bfrag*)&Ps[rf * 16 + ln16][ks * 32 + hi16 * 8];
        #pragma unroll
        for (int ks = 0; ks < 2; ++ks)
            #pragma unroll
            for (int rf = 0; rf < 2; ++rf)
                #pragma unroll
                for (int dt = 0; dt < 4; ++dt)
                    acc[rf][dt] = __builtin_amdgcn_mfma_f32_16x16x32_bf16(pf[rf][ks], vf[dt][ks], acc[rf][dt], 0, 0, 0);
    }

    // ---- epilogue: reduce l across the 16-lane groups, normalize, store ----
    #pragma unroll
    for (int rf = 0; rf < 2; ++rf)
        #pragma unroll
        for (int e = 0; e < 4; ++e) {
            float l = lrow[rf][e];
            l += __shfl_xor(l, 1);
            l += __shfl_xor(l, 2);
            l += __shfl_xor(l, 4);
            l += __shfl_xor(l, 8);
            const float inv = 1.0f / l;
            const size_t row = qrow0 + tok0 + rf * 16 + hi16 * 4 + e;
            #pragma unroll
            for (int dt = 0; dt < 4; ++dt)
                att[row * C_DIM + h * HD + dt * 16 + ln16] = f2bf(acc[rf][dt][e] * inv);
        }
}

// ---------------------------------------------------------------------------
// Fused residual add + LayerNorm; optionally also emits bf16 copy.
// ---------------------------------------------------------------------------
template<int WB>
__global__ __launch_bounds__(256)
void ln_residual_kernel(const float* __restrict__ A, const float* __restrict__ R,
                        const float* __restrict__ gamma, const float* __restrict__ beta,
                        float* __restrict__ out, unsigned short* __restrict__ outb, int Mrows)
{
    const int lane = threadIdx.x & 63;
    const int wv   = threadIdx.x >> 6;
    const int row  = blockIdx.x * 4 + wv;
    if (row >= Mrows) return;
    const size_t off = (size_t)row * C_DIM;

    float v[6];
    float sum = 0.0f;
    #pragma unroll
    for (int j = 0; j < 6; ++j) {
        const int c = lane + 64 * j;
        v[j] = A[off + c] + R[off + c];
        sum += v[j];
    }
    #pragma unroll
    for (int o = 1; o < 64; o <<= 1) sum += __shfl_xor(sum, o);
    const float mu = sum * (1.0f / C_DIM);

    float sq = 0.0f;
    #pragma unroll
    for (int j = 0; j < 6; ++j) { const float d = v[j] - mu; sq = fmaf(d, d, sq); }
    #pragma unroll
    for (int o = 1; o < 64; o <<= 1) sq += __shfl_xor(sq, o);
    const float rstd = rsqrtf(sq * (1.0f / C_DIM) + LN_EPS);

    #pragma unroll
    for (int j = 0; j < 6; ++j) {
        const int c = lane + 64 * j;
        const float r = (v[j] - mu) * rstd * gamma[c] + beta[c];
        out[off + c] = r;
        if (WB) outb[off + c] = f2bf(r);
    }
}

// ---------------------------------------------------------------------------
extern "C" void kernel_launch(void* const* d_in, const int* in_sizes, int n_in,
                              void* d_out, int out_size, void* d_ws, size_t ws_size,
                              hipStream_t stream)
{
    const float* x   = (const float*)d_in[0];
    const float* Wq  = (const float*)d_in[1];
    const float* Wk  = (const float*)d_in[2];
    const float* Wv  = (const float*)d_in[3];
    const float* Wo  = (const float*)d_in[4];
    const float* bo  = (const float*)d_in[5];
    const float* W1  = (const float*)d_in[6];
    const float* b1  = (const float*)d_in[7];
    const float* W2  = (const float*)d_in[8];
    const float* b2  = (const float*)d_in[9];
    const float* g1  = (const float*)d_in[10];
    const float* be1 = (const float*)d_in[11];
    const float* g2  = (const float*)d_in[12];
    const float* be2 = (const float*)d_in[13];
    float* out = (float*)d_out;

    const int M = BATCH * TSEQ;                  // 8192
    const size_t MC = (size_t)M * C_DIM;

    // ---- workspace layout (bytes) ----
    char* ws = (char*)d_ws;
    unsigned short* qkv = (unsigned short*)ws;                       // M*1152*2 = 18.87 MB
    unsigned short* vt  = (unsigned short*)(ws + (size_t)M*1152*2);  // 24*64*2048*2 = 6.29 MB
    unsigned short* att = (unsigned short*)(ws + (size_t)M*1152*2 + (size_t)BATCH*HEADS*HD*TSEQ*2); // 6.29 MB
    unsigned short* h1  = (unsigned short*)ws;                       // M*1536*2 = 25.17 MB, aliases qkv+vt
    char* p2 = ws + (size_t)M*1152*2 + (size_t)BATCH*HEADS*HD*TSEQ*2 + MC*2;   // = 31.46 MB mark
    unsigned short* xb  = (unsigned short*)p2;                       // MC bf16
    float* y   = (float*)(p2 + MC*2);                                // MC f32
    float* x1  = (float*)(p2 + MC*2 + MC*4);                         // MC f32
    unsigned short* x1b = (unsigned short*)(p2 + MC*2 + 2*MC*4);     // MC bf16
    char* p3 = p2 + MC*2 + 2*MC*4 + MC*2;
    unsigned short* Wqkv_t = (unsigned short*)p3;                        // [1152][384]
    unsigned short* Wo_t   = Wqkv_t + (size_t)3*C_DIM*C_DIM;             // [384][384]
    unsigned short* W1_t   = Wo_t   + (size_t)C_DIM*C_DIM;               // [1536][384]
    unsigned short* W2_t   = W1_t   + (size_t)FF_DIM*C_DIM;              // [384][1536]

    dim3 b256(256), b328(32, 8);

    // ---- weight transposes (f32 -> bf16 [N][K]) ----
    transpose_w<<<dim3(C_DIM/32, C_DIM/32), b328, 0, stream>>>(Wq, Wqkv_t,                     C_DIM, C_DIM);
    transpose_w<<<dim3(C_DIM/32, C_DIM/32), b328, 0, stream>>>(Wk, Wqkv_t + (size_t)C_DIM*C_DIM,   C_DIM, C_DIM);
    transpose_w<<<dim3(C_DIM/32, C_DIM/32), b328, 0, stream>>>(Wv, Wqkv_t + (size_t)2*C_DIM*C_DIM, C_DIM, C_DIM);
    transpose_w<<<dim3(C_DIM/32, C_DIM/32), b328, 0, stream>>>(Wo, Wo_t, C_DIM, C_DIM);
    transpose_w<<<dim3(FF_DIM/32, C_DIM/32), b328, 0, stream>>>(W1, W1_t, C_DIM, FF_DIM);
    transpose_w<<<dim3(C_DIM/32, FF_DIM/32), b328, 0, stream>>>(W2, W2_t, FF_DIM, C_DIM);

    // ---- x -> bf16 ----
    cvt_f32_bf16_x4<<<dim3((MC/4 + 255)/256), b256, 0, stream>>>(x, xb, (int)(MC/4));

    // ---- qkv = xb @ Wqkv ----
    gemm_l2<4, 1, 0, 0><<<dim3(3*C_DIM/64, M/256), b256, 0, stream>>>(
        xb, Wqkv_t, nullptr, qkv, M, 3*C_DIM, C_DIM);

    // ---- V transpose ----
    vtrans_kernel<<<dim3(TSEQ/32, HD/32, BATCH*HEADS), b328, 0, stream>>>(qkv, vt);

    // ---- attention ----
    attn_kernel<<<dim3(BATCH*HEADS*64), dim3(64), 0, stream>>>(qkv, vt, att);

    // ---- y = att @ Wo + bo ----
    gemm_l2<2, 0, 1, 0><<<dim3(C_DIM/32, M/256), b256, 0, stream>>>(
        att, Wo_t, bo, y, M, C_DIM, C_DIM);

    // ---- x1 = LN(x + y), also bf16 ----
    ln_residual_kernel<1><<<dim3(M/4), b256, 0, stream>>>(x, y, g1, be1, x1, x1b, M);

    // ---- h1 = relu(x1b @ W1 + b1) ----
    gemm_l2<4, 1, 1, 1><<<dim3(FF_DIM/64, M/256), b256, 0, stream>>>(
        x1b, W1_t, b1, h1, M, FF_DIM, C_DIM);

    // ---- y = h1 @ W2 + b2 ----
    gemm_l2<2, 0, 1, 0><<<dim3(C_DIM/32, M/256), b256, 0, stream>>>(
        h1, W2_t, b2, y, M, C_DIM, FF_DIM);

    // ---- out = LN(x1 + y) ----
    ln_residual_kernel<0><<<dim3(M/4), b256, 0, stream>>>(x1, y, g2, be2, out, nullptr, M);
}

// Round 7
// 217.261 us; speedup vs baseline: 1.2967x; 1.2967x over previous
//
#include <hip/hip_runtime.h>

#define C_DIM  384
#define HEADS  6
#define HD     64
#define FF_DIM 1536
#define LN_EPS 1e-3f
#define TSEQ   2048
#define BATCH  4
#define LOG2E  1.4426950408889634f

typedef __attribute__((ext_vector_type(4))) float          f32x4;
typedef __attribute__((ext_vector_type(4))) float          float4_t;
typedef __attribute__((ext_vector_type(8))) short          bfrag;     // 8 bf16
typedef __attribute__((ext_vector_type(4))) unsigned short ushort4_t;
typedef __attribute__((ext_vector_type(8))) unsigned short ushort8_t;

__device__ inline unsigned short f2bf(float f) {
    unsigned int u = __builtin_bit_cast(unsigned int, f);
    u += 0x7fff + ((u >> 16) & 1);          // RNE
    return (unsigned short)(u >> 16);
}

// async global->LDS, 16 B per lane. LDS dest is wave-uniform base + lane*16.
__device__ inline void gload_lds16(const void* g, void* l) {
    __builtin_amdgcn_global_load_lds(
        (const __attribute__((address_space(1))) unsigned int*)g,
        (__attribute__((address_space(3))) unsigned int*)l,
        16, 0, 0);
}

// ---------------------------------------------------------------------------
// Batched transpose+convert of the four 384x384 weights: W[K][N] f32 -> Wt[N][K] bf16.
// block (32,8), grid (12, 12, 4).
// ---------------------------------------------------------------------------
__global__ __launch_bounds__(256)
void transpose_w4(const float* __restrict__ Wq, const float* __restrict__ Wk,
                  const float* __restrict__ Wv, const float* __restrict__ Wo,
                  unsigned short* __restrict__ Dq, unsigned short* __restrict__ Dk,
                  unsigned short* __restrict__ Dv, unsigned short* __restrict__ Do_)
{
    __shared__ float tile[32][33];
    const int z = blockIdx.z;
    const float* W = z == 0 ? Wq : (z == 1 ? Wk : (z == 2 ? Wv : Wo));
    unsigned short* D = z == 0 ? Dq : (z == 1 ? Dk : (z == 2 ? Dv : Do_));
    const int tx = threadIdx.x, ty = threadIdx.y;
    const int n0 = blockIdx.x * 32, k0 = blockIdx.y * 32;
    #pragma unroll
    for (int i = 0; i < 32; i += 8)
        tile[ty + i][tx] = W[(size_t)(k0 + ty + i) * C_DIM + n0 + tx];
    __syncthreads();
    #pragma unroll
    for (int i = 0; i < 32; i += 8)
        D[(size_t)(n0 + ty + i) * C_DIM + k0 + tx] = f2bf(tile[tx][ty + i]);
}

// generic transpose: W[K][N] f32 -> Wt[N][K] bf16
__global__ __launch_bounds__(256)
void transpose_w(const float* __restrict__ W, unsigned short* __restrict__ Wt, int K, int N)
{
    __shared__ float tile[32][33];
    const int tx = threadIdx.x, ty = threadIdx.y;
    const int n0 = blockIdx.x * 32, k0 = blockIdx.y * 32;
    #pragma unroll
    for (int i = 0; i < 32; i += 8)
        tile[ty + i][tx] = W[(size_t)(k0 + ty + i) * N + n0 + tx];
    __syncthreads();
    #pragma unroll
    for (int i = 0; i < 32; i += 8)
        Wt[(size_t)(n0 + ty + i) * K + k0 + tx] = f2bf(tile[tx][ty + i]);
}

__global__ __launch_bounds__(256)
void cvt_f32_bf16_x4(const float* __restrict__ in, unsigned short* __restrict__ out, int n4)
{
    int i = blockIdx.x * 256 + threadIdx.x;
    if (i >= n4) return;
    float4_t v = ((const float4_t*)in)[i];
    ushort4_t o = { f2bf(v.x), f2bf(v.y), f2bf(v.z), f2bf(v.w) };
    ((ushort4_t*)out)[i] = o;
}

// ---------------------------------------------------------------------------
// V transpose: qkv v-columns -> vt[bh][d][t] bf16.
// ---------------------------------------------------------------------------
__global__ __launch_bounds__(256)
void vtrans_kernel(const unsigned short* __restrict__ qkv, unsigned short* __restrict__ vt)
{
    __shared__ unsigned short tile[32][34];
    const int tx = threadIdx.x, ty = threadIdx.y;
    const int bh = blockIdx.z, b = bh / HEADS, h = bh % HEADS;
    const int t0 = blockIdx.x * 32, d0 = blockIdx.y * 32;
    #pragma unroll
    for (int i = 0; i < 32; i += 8)
        tile[ty + i][tx] = qkv[(size_t)(b * TSEQ + t0 + ty + i) * 1152 + 2 * C_DIM + h * HD + d0 + tx];
    __syncthreads();
    #pragma unroll
    for (int i = 0; i < 32; i += 8)
        vt[((size_t)bh * HD + d0 + ty + i) * TSEQ + t0 + tx] = tile[tx][ty + i];
}

// ---------------------------------------------------------------------------
// LDS-staged bf16 MFMA GEMM (m97 structure).
// C[M,N] = A[M,K] @ Bt[N,K]^T (+bias)(+relu). BM=BN=128, BK=64, 4 waves 2x2.
// Staging via global_load_lds in FRAGMENT-MAJOR order: LDS unit f*1024+lane*16
// holds exactly the bytes ds_read_b128 wants -> linear reads, 0 bank conflicts.
// A, Bt bf16, K-contiguous. M%128==0, N%128==0, K%64==0.
// ---------------------------------------------------------------------------
template<int OBF16, int BIAS, int RELU>
__global__ __launch_bounds__(256)
void gemm_lds(const unsigned short* __restrict__ A, const unsigned short* __restrict__ Bt,
              const float* __restrict__ bias, void* __restrict__ Cv,
              int M, int N, int K)
{
    __shared__ __align__(16) unsigned short As[16 * 512];   // 16 frags x 1KB
    __shared__ __align__(16) unsigned short Bs[16 * 512];

    const int t = threadIdx.x, lane = t & 63, w = t >> 6;
    const int ln16 = lane & 15, hi16 = lane >> 4;
    const int wr = w >> 1, wc = w & 1;
    const int row0 = blockIdx.y * 128, col0 = blockIdx.x * 128;

    // per-lane staging source coords for this wave's 4 frag ids f = w*4+i:
    //   f = ks*8 + rf;  unit(lane) = [rf*16 + (lane&15)][ks*32 + (lane>>4)*8]
    f32x4 acc[4][4] = {};

    for (int k0 = 0; k0 < K; k0 += 64) {
        #pragma unroll
        for (int i = 0; i < 4; ++i) {
            const int f  = w * 4 + i;
            const int ks = f >> 3, rf = f & 7;
            const int row = rf * 16 + ln16;
            const int kc  = k0 + ks * 32 + hi16 * 8;
            gload_lds16(&A [(size_t)(row0 + row) * K + kc], &As[f * 512]);
            gload_lds16(&Bt[(size_t)(col0 + row) * K + kc], &Bs[f * 512]);
        }
        __syncthreads();
        #pragma unroll
        for (int ks = 0; ks < 2; ++ks) {
            bfrag a[4], b[4];
            #pragma unroll
            for (int i = 0; i < 4; ++i)
                a[i] = *(const bfrag*)&As[(ks * 8 + wr * 4 + i) * 512 + lane * 8];
            #pragma unroll
            for (int j = 0; j < 4; ++j)
                b[j] = *(const bfrag*)&Bs[(ks * 8 + wc * 4 + j) * 512 + lane * 8];
            #pragma unroll
            for (int i = 0; i < 4; ++i)
                #pragma unroll
                for (int j = 0; j < 4; ++j)
                    acc[i][j] = __builtin_amdgcn_mfma_f32_16x16x32_bf16(a[i], b[j], acc[i][j], 0, 0, 0);
        }
        __syncthreads();
    }

    // epilogue: D layout col = lane&15, row = (lane>>4)*4 + e
    #pragma unroll
    for (int j = 0; j < 4; ++j) {
        const int col = col0 + wc * 64 + j * 16 + ln16;
        const float bv = BIAS ? bias[col] : 0.0f;
        #pragma unroll
        for (int i = 0; i < 4; ++i) {
            #pragma unroll
            for (int e = 0; e < 4; ++e) {
                const int row = row0 + wr * 64 + i * 16 + hi16 * 4 + e;
                float v = acc[i][j][e] + bv;
                if (RELU) v = fmaxf(v, 0.0f);
                if (OBF16) ((unsigned short*)Cv)[(size_t)row * N + col] = f2bf(v);
                else       ((float*)Cv)[(size_t)row * N + col] = v;
            }
        }
    }
}

// ---------------------------------------------------------------------------
// Wave-independent flash attention (unchanged from round 4).
// ---------------------------------------------------------------------------
__global__ __launch_bounds__(64)
void attn_kernel(const unsigned short* __restrict__ qkv,
                 const unsigned short* __restrict__ vt,
                 unsigned short* __restrict__ att)
{
    __shared__ __align__(16) unsigned short Ps[32][72];
    const int lane = threadIdx.x;
    const int ln16 = lane & 15, hi16 = lane >> 4;
    const int bid = blockIdx.x;            // 0..1535
    const int xcd = bid & 7;
    const int i2  = bid >> 3;              // 0..191
    const int bh  = xcd * 3 + (i2 >> 6);   // 3 bh per XCD -> 1.5 MB KV per L2
    const int qw  = 63 - (i2 & 63);        // descending: heavy waves first
    const int b   = bh / HEADS, h = bh % HEADS;
    const int tok0 = qw * 32;
    const size_t qrow0 = (size_t)b * TSEQ;

    bfrag qf[2][2];
    #pragma unroll
    for (int rf = 0; rf < 2; ++rf)
        #pragma unroll
        for (int ks = 0; ks < 2; ++ks)
            qf[rf][ks] = *(const bfrag*)&qkv[(qrow0 + tok0 + rf * 16 + ln16) * 1152 + h * HD + ks * 32 + hi16 * 8];

    f32x4 acc[2][4] = {};
    float mrow[2][4], lrow[2][4];
    #pragma unroll
    for (int rf = 0; rf < 2; ++rf)
        #pragma unroll
        for (int e = 0; e < 4; ++e) { mrow[rf][e] = -1e30f; lrow[rf][e] = 0.0f; }

    const int NT = (qw >> 1) + 1;
    const unsigned short* Kbase = qkv + qrow0 * 1152 + C_DIM + h * HD;
    const unsigned short* Vbase = vt + (size_t)bh * HD * TSEQ;

    bfrag kf[4][2];
    #pragma unroll
    for (int jt = 0; jt < 4; ++jt)
        #pragma unroll
        for (int ks = 0; ks < 2; ++ks)
            kf[jt][ks] = *(const bfrag*)&Kbase[(size_t)(jt * 16 + ln16) * 1152 + ks * 32 + hi16 * 8];

    for (int kt = 0; kt < NT; ++kt) {
        f32x4 sf[2][4] = {};
        #pragma unroll
        for (int jt = 0; jt < 4; ++jt)
            #pragma unroll
            for (int ks = 0; ks < 2; ++ks) {
                sf[0][jt] = __builtin_amdgcn_mfma_f32_16x16x32_bf16(qf[0][ks], kf[jt][ks], sf[0][jt], 0, 0, 0);
                sf[1][jt] = __builtin_amdgcn_mfma_f32_16x16x32_bf16(qf[1][ks], kf[jt][ks], sf[1][jt], 0, 0, 0);
            }

        bfrag vf[4][2];
        #pragma unroll
        for (int dt = 0; dt < 4; ++dt)
            #pragma unroll
            for (int ks = 0; ks < 2; ++ks)
                vf[dt][ks] = *(const bfrag*)&Vbase[(size_t)(dt * 16 + ln16) * TSEQ + kt * 64 + ks * 32 + hi16 * 8];

        const bool last = (kt == NT - 1);
        float p[2][4][4];
        #pragma unroll
        for (int rf = 0; rf < 2; ++rf)
            #pragma unroll
            for (int jt = 0; jt < 4; ++jt)
                #pragma unroll
                for (int e = 0; e < 4; ++e) {
                    float sv = sf[rf][jt][e] * (0.125f * LOG2E);
                    if (last) {
                        const int key = kt * 64 + jt * 16 + ln16;
                        const int row = tok0 + rf * 16 + hi16 * 4 + e;
                        if (key > row) sv = -1e30f;
                    }
                    p[rf][jt][e] = sv;
                }

        float lmax[2][4];
        bool need = false;
        #pragma unroll
        for (int rf = 0; rf < 2; ++rf)
            #pragma unroll
            for (int e = 0; e < 4; ++e) {
                float mx = fmaxf(fmaxf(p[rf][0][e], p[rf][1][e]), fmaxf(p[rf][2][e], p[rf][3][e]));
                lmax[rf][e] = mx;
                need = need || (mx > mrow[rf][e] + 8.0f);
            }
        if (__any(need)) {
            #pragma unroll
            for (int rf = 0; rf < 2; ++rf)
                #pragma unroll
                for (int e = 0; e < 4; ++e) {
                    float rm = lmax[rf][e];
                    rm = fmaxf(rm, __shfl_xor(rm, 1));
                    rm = fmaxf(rm, __shfl_xor(rm, 2));
                    rm = fmaxf(rm, __shfl_xor(rm, 4));
                    rm = fmaxf(rm, __shfl_xor(rm, 8));
                    const float mn = fmaxf(mrow[rf][e], rm);
                    const float corr = exp2f(mrow[rf][e] - mn);
                    mrow[rf][e] = mn;
                    lrow[rf][e] *= corr;
                    #pragma unroll
                    for (int dt = 0; dt < 4; ++dt) acc[rf][dt][e] *= corr;
                }
        }

        if (kt + 1 < NT) {
            const unsigned short* Kn = Kbase + (size_t)(kt + 1) * 64 * 1152;
            #pragma unroll
            for (int jt = 0; jt < 4; ++jt)
                #pragma unroll
                for (int ks = 0; ks < 2; ++ks)
                    kf[jt][ks] = *(const bfrag*)&Kn[(size_t)(jt * 16 + ln16) * 1152 + ks * 32 + hi16 * 8];
        }

        #pragma unroll
        for (int rf = 0; rf < 2; ++rf)
            #pragma unroll
            for (int jt = 0; jt < 4; ++jt)
                #pragma unroll
                for (int e = 0; e < 4; ++e) {
                    const float pe = exp2f(p[rf][jt][e] - mrow[rf][e]);
                    lrow[rf][e] += pe;
                    Ps[rf * 16 + hi16 * 4 + e][jt * 16 + ln16] = f2bf(pe);
                }

        bfrag pf[2][2];
        #pragma unroll
        for (int rf = 0; rf < 2; ++rf)
            #pragma unroll
            for (int ks = 0; ks < 2; ++ks)
                pf[rf][ks] = *(const bfrag*)&Ps[rf * 16 + ln16][ks * 32 + hi16 * 8];
        #pragma unroll
        for (int ks = 0; ks < 2; ++ks)
            #pragma unroll
            for (int rf = 0; rf < 2; ++rf)
                #pragma unroll
                for (int dt = 0; dt < 4; ++dt)
                    acc[rf][dt] = __builtin_amdgcn_mfma_f32_16x16x32_bf16(pf[rf][ks], vf[dt][ks], acc[rf][dt], 0, 0, 0);
    }

    #pragma unroll
    for (int rf = 0; rf < 2; ++rf)
        #pragma unroll
        for (int e = 0; e < 4; ++e) {
            float l = lrow[rf][e];
            l += __shfl_xor(l, 1);
            l += __shfl_xor(l, 2);
            l += __shfl_xor(l, 4);
            l += __shfl_xor(l, 8);
            const float inv = 1.0f / l;
            const size_t row = qrow0 + tok0 + rf * 16 + hi16 * 4 + e;
            #pragma unroll
            for (int dt = 0; dt < 4; ++dt)
                att[row * C_DIM + h * HD + dt * 16 + ln16] = f2bf(acc[rf][dt][e] * inv);
        }
}

// ---------------------------------------------------------------------------
// Fused residual add + LayerNorm; optionally also emits bf16 copy.
// ---------------------------------------------------------------------------
template<int WB>
__global__ __launch_bounds__(256)
void ln_residual_kernel(const float* __restrict__ A, const float* __restrict__ R,
                        const float* __restrict__ gamma, const float* __restrict__ beta,
                        float* __restrict__ out, unsigned short* __restrict__ outb, int Mrows)
{
    const int lane = threadIdx.x & 63;
    const int wv   = threadIdx.x >> 6;
    const int row  = blockIdx.x * 4 + wv;
    if (row >= Mrows) return;
    const size_t off = (size_t)row * C_DIM;

    float v[6];
    float sum = 0.0f;
    #pragma unroll
    for (int j = 0; j < 6; ++j) {
        const int c = lane + 64 * j;
        v[j] = A[off + c] + R[off + c];
        sum += v[j];
    }
    #pragma unroll
    for (int o = 1; o < 64; o <<= 1) sum += __shfl_xor(sum, o);
    const float mu = sum * (1.0f / C_DIM);

    float sq = 0.0f;
    #pragma unroll
    for (int j = 0; j < 6; ++j) { const float d = v[j] - mu; sq = fmaf(d, d, sq); }
    #pragma unroll
    for (int o = 1; o < 64; o <<= 1) sq += __shfl_xor(sq, o);
    const float rstd = rsqrtf(sq * (1.0f / C_DIM) + LN_EPS);

    #pragma unroll
    for (int j = 0; j < 6; ++j) {
        const int c = lane + 64 * j;
        const float r = (v[j] - mu) * rstd * gamma[c] + beta[c];
        out[off + c] = r;
        if (WB) outb[off + c] = f2bf(r);
    }
}

// ---------------------------------------------------------------------------
extern "C" void kernel_launch(void* const* d_in, const int* in_sizes, int n_in,
                              void* d_out, int out_size, void* d_ws, size_t ws_size,
                              hipStream_t stream)
{
    const float* x   = (const float*)d_in[0];
    const float* Wq  = (const float*)d_in[1];
    const float* Wk  = (const float*)d_in[2];
    const float* Wv  = (const float*)d_in[3];
    const float* Wo  = (const float*)d_in[4];
    const float* bo  = (const float*)d_in[5];
    const float* W1  = (const float*)d_in[6];
    const float* b1  = (const float*)d_in[7];
    const float* W2  = (const float*)d_in[8];
    const float* b2  = (const float*)d_in[9];
    const float* g1  = (const float*)d_in[10];
    const float* be1 = (const float*)d_in[11];
    const float* g2  = (const float*)d_in[12];
    const float* be2 = (const float*)d_in[13];
    float* out = (float*)d_out;

    const int M = BATCH * TSEQ;                  // 8192
    const size_t MC = (size_t)M * C_DIM;

    // ---- workspace layout (bytes) ----
    char* ws = (char*)d_ws;
    unsigned short* qkv = (unsigned short*)ws;                       // M*1152*2 = 18.87 MB
    unsigned short* vt  = (unsigned short*)(ws + (size_t)M*1152*2);  // 24*64*2048*2 = 6.29 MB
    unsigned short* att = (unsigned short*)(ws + (size_t)M*1152*2 + (size_t)BATCH*HEADS*HD*TSEQ*2); // 6.29 MB
    unsigned short* h1  = (unsigned short*)ws;                       // M*1536*2 = 25.17 MB, aliases qkv+vt
    char* p2 = ws + (size_t)M*1152*2 + (size_t)BATCH*HEADS*HD*TSEQ*2 + MC*2;   // = 31.46 MB mark
    unsigned short* xb  = (unsigned short*)p2;                       // MC bf16
    float* y   = (float*)(p2 + MC*2);                                // MC f32
    float* x1  = (float*)(p2 + MC*2 + MC*4);                         // MC f32
    unsigned short* x1b = (unsigned short*)(p2 + MC*2 + 2*MC*4);     // MC bf16
    char* p3 = p2 + MC*2 + 2*MC*4 + MC*2;
    unsigned short* Wqkv_t = (unsigned short*)p3;                        // [1152][384]
    unsigned short* Wo_t   = Wqkv_t + (size_t)3*C_DIM*C_DIM;             // [384][384]
    unsigned short* W1_t   = Wo_t   + (size_t)C_DIM*C_DIM;               // [1536][384]
    unsigned short* W2_t   = W1_t   + (size_t)FF_DIM*C_DIM;              // [384][1536]

    dim3 b256(256), b328(32, 8);

    // ---- weight transposes (f32 -> bf16 [N][K]) ----
    transpose_w4<<<dim3(C_DIM/32, C_DIM/32, 4), b328, 0, stream>>>(
        Wq, Wk, Wv, Wo,
        Wqkv_t, Wqkv_t + (size_t)C_DIM*C_DIM, Wqkv_t + (size_t)2*C_DIM*C_DIM, Wo_t);
    transpose_w<<<dim3(FF_DIM/32, C_DIM/32), b328, 0, stream>>>(W1, W1_t, C_DIM, FF_DIM);
    transpose_w<<<dim3(C_DIM/32, FF_DIM/32), b328, 0, stream>>>(W2, W2_t, FF_DIM, C_DIM);

    // ---- x -> bf16 ----
    cvt_f32_bf16_x4<<<dim3((MC/4 + 255)/256), b256, 0, stream>>>(x, xb, (int)(MC/4));

    // ---- qkv = xb @ Wqkv ----
    gemm_lds<1, 0, 0><<<dim3(3*C_DIM/128, M/128), b256, 0, stream>>>(
        xb, Wqkv_t, nullptr, qkv, M, 3*C_DIM, C_DIM);

    // ---- V transpose ----
    vtrans_kernel<<<dim3(TSEQ/32, HD/32, BATCH*HEADS), b328, 0, stream>>>(qkv, vt);

    // ---- attention ----
    attn_kernel<<<dim3(BATCH*HEADS*64), dim3(64), 0, stream>>>(qkv, vt, att);

    // ---- y = att @ Wo + bo ----
    gemm_lds<0, 1, 0><<<dim3(C_DIM/128, M/128), b256, 0, stream>>>(
        att, Wo_t, bo, y, M, C_DIM, C_DIM);

    // ---- x1 = LN(x + y), also bf16 ----
    ln_residual_kernel<1><<<dim3(M/4), b256, 0, stream>>>(x, y, g1, be1, x1, x1b, M);

    // ---- h1 = relu(x1b @ W1 + b1) ----
    gemm_lds<1, 1, 1><<<dim3(FF_DIM/128, M/128), b256, 0, stream>>>(
        x1b, W1_t, b1, h1, M, FF_DIM, C_DIM);

    // ---- y = h1 @ W2 + b2 ----
    gemm_lds<0, 1, 0><<<dim3(C_DIM/128, M/128), b256, 0, stream>>>(
        h1, W2_t, b2, y, M, C_DIM, FF_DIM);

    // ---- out = LN(x1 + y) ----
    ln_residual_kernel<0><<<dim3(M/4), b256, 0, stream>>>(x1, y, g2, be2, out, nullptr, M);
}